// Round 9
// baseline (588.553 us; speedup 1.0000x reference)
//
#include <hip/hip_runtime.h>
#include <hip/hip_bf16.h>
#include <math.h>

#define NH   8
#define NSEQ 4096
#define NB   2
#define HID  256
#define VD   32
#define RANK 409      // 0-indexed; pos = 0.1*(4096-1) = 409.5 -> lerp(s[409],s[410],0.5)
#define NBIN 128      // candidate-space histogram bins (per wave)
#define CAND 704      // per-wave candidate cap (mean 480, sd 20.6 -> 10.9 sigma)
#define TG   0.1171875f  // raw-space threshold guess (scale-independent, scale>0)

typedef float floatx4 __attribute__((ext_vector_type(4)));

__device__ __forceinline__ unsigned mbcnt64(unsigned long long m) {
  return __builtin_amdgcn_mbcnt_hi((unsigned)(m >> 32),
                                   __builtin_amdgcn_mbcnt_lo((unsigned)m, 0u));
}
__device__ __forceinline__ float wred_min(float x) {
#pragma unroll
  for (int d = 32; d; d >>= 1) x = fminf(x, __shfl_xor(x, d, 64));
  return x;
}
__device__ __forceinline__ float wred_sum(float x) {
#pragma unroll
  for (int d = 32; d; d >>= 1) x += __shfl_xor(x, d, 64);
  return x;
}
__device__ __forceinline__ float gelu_tanh(float x) {
  float x3 = x * x * x;
  float inner = 0.7978845608028654f * (x + 0.044715f * x3);
  return 0.5f * x * (1.0f + tanhf(inner));
}

// ---------------- kernel A: value[h][n][b*32+k] = x @ weight; + scales ------

__global__ __launch_bounds__(256) void value_kernel(
    const float* __restrict__ x, const float* __restrict__ w,
    const float* __restrict__ r, float* __restrict__ value,
    float* __restrict__ scales) {
  const int tid = threadIdx.x;

  if (blockIdx.x == 0 && tid < NH) {
    double rv = (double)r[tid];
    const float c0 = (float)(0.25 * 3.141592653589793 * (1.0 - 1e-07));
    float s1 = (float)sin(rv);
    float t = c0 * (1.0f + s1);
    scales[tid] = (float)tan((double)t);
  }

  const int n0 = blockIdx.x * 8;
  __shared__ float sx[NB][8][HID];
#pragma unroll
  for (int i = 0; i < 16; i++) {
    int idx = i * 256 + tid;
    int b = idx >> 11;
    int rem = idx & 2047;
    int nn = rem >> 8;
    int j = rem & 255;
    sx[b][nn][j] = x[((size_t)b * NSEQ + n0 + nn) * HID + j];
  }
  __syncthreads();

  const int h = tid >> 5, k = tid & 31;
  float acc[NB][8];
#pragma unroll
  for (int b = 0; b < NB; b++)
#pragma unroll
    for (int nn = 0; nn < 8; nn++) acc[b][nn] = 0.f;

  const float* wp = w + (size_t)h * HID * VD + k;
  for (int j4 = 0; j4 < HID; j4 += 4) {
    float wv0 = wp[(size_t)(j4 + 0) * VD];
    float wv1 = wp[(size_t)(j4 + 1) * VD];
    float wv2 = wp[(size_t)(j4 + 2) * VD];
    float wv3 = wp[(size_t)(j4 + 3) * VD];
#pragma unroll
    for (int b = 0; b < NB; b++) {
#pragma unroll
      for (int nn = 0; nn < 8; nn++) {
        const float4 xv = *reinterpret_cast<const float4*>(&sx[b][nn][j4]);
        float a = acc[b][nn];
        a = fmaf(xv.x, wv0, a);
        a = fmaf(xv.y, wv1, a);
        a = fmaf(xv.z, wv2, a);
        a = fmaf(xv.w, wv3, a);
        acc[b][nn] = a;
      }
    }
  }
#pragma unroll
  for (int b = 0; b < NB; b++)
#pragma unroll
    for (int nn = 0; nn < 8; nn++)
      value[((size_t)h * NSEQ + n0 + nn) * (NB * VD) + b * VD + k] = acc[b][nn];
}

// ---------------- kernel B: ONE WAVE PER ROW, zero __syncthreads ------------

__global__ __launch_bounds__(256, 6) void attn_kernel(
    const float* __restrict__ m_dist, const float* __restrict__ value,
    const float* __restrict__ scales, float* __restrict__ out) {
  const int tid = threadIdx.x;
  const int lane = tid & 63;
  const int wv = tid >> 6;
  // 8192 blocks of 4 independent waves; bid&7 -> head == XCD (value L2-resident)
  const int bid = blockIdx.x;
  const int h = bid & 7;
  const int q = (bid >> 3) * 4 + wv;

  __shared__ float2 s_cand[4][CAND];   // 22528 B: per-wave (v_scaled, byteoff)->(w, byteoff)
  __shared__ unsigned s_hist[4][NBIN]; // 2048 B
  __shared__ float s_small[4][48];     // 768 B
  __shared__ unsigned s_cnt[4];        // 16 B   (total 25360 B -> 6 blocks/CU)

  float2* sc = s_cand[wv];
  unsigned* sh = s_hist[wv];
  float* ssm = s_small[wv];
  unsigned* scn = &s_cnt[wv];

  const float scale = scales[h];
  const floatx4* row4 =
      reinterpret_cast<const floatx4*>(m_dist + ((size_t)(h * NSEQ + q)) * NSEQ) + lane;

  // ---- stream 16 chunks: raw-space candidate compaction via ballot prefix ----
  // raw order == scaled order (scale>0, fl monotone), so select on raw u.
  float Traw = TG;
  float lo = 0.f, hi = 1.0f;
  float rmin;
  unsigned nc;
  for (int attempt = 0;; ++attempt) {
    rmin = INFINITY;
    nc = 0;
    for (int ch = 0; ch < 16; ++ch) {
      floatx4 t4 = __builtin_nontemporal_load(row4 + ch * 64);
      const int nb = ch * 256 + lane * 4;
      float u0 = t4.x, u1 = t4.y, u2 = t4.z, u3 = t4.w;
      rmin = fminf(fminf(fminf(rmin, u0), fminf(u1, u2)), u3);
      {
        bool s = (u0 <= Traw);
        unsigned long long m = __ballot(s);
        if (s) { unsigned p = nc + mbcnt64(m); if (p < CAND) sc[p] = make_float2(u0 * scale, __int_as_float((nb + 0) << 8)); }
        nc += (unsigned)__popcll(m);
      }
      {
        bool s = (u1 <= Traw);
        unsigned long long m = __ballot(s);
        if (s) { unsigned p = nc + mbcnt64(m); if (p < CAND) sc[p] = make_float2(u1 * scale, __int_as_float((nb + 1) << 8)); }
        nc += (unsigned)__popcll(m);
      }
      {
        bool s = (u2 <= Traw);
        unsigned long long m = __ballot(s);
        if (s) { unsigned p = nc + mbcnt64(m); if (p < CAND) sc[p] = make_float2(u2 * scale, __int_as_float((nb + 2) << 8)); }
        nc += (unsigned)__popcll(m);
      }
      {
        bool s = (u3 <= Traw);
        unsigned long long m = __ballot(s);
        if (s) { unsigned p = nc + mbcnt64(m); if (p < CAND) sc[p] = make_float2(u3 * scale, __int_as_float((nb + 3) << 8)); }
        nc += (unsigned)__popcll(m);
      }
    }
    rmin = wred_min(rmin);
    if ((nc >= (unsigned)(RANK + 2) && nc <= CAND) || attempt >= 24) break;
    if (nc < (unsigned)(RANK + 2)) lo = Traw; else hi = Traw;
    float mid = 0.5f * (lo + hi);
    if (!(mid > lo && mid < hi)) break;  // interval collapsed (massive ties; unreachable)
    Traw = mid;
  }
  if (nc > CAND) nc = CAND;  // safety (unreachable on this data)
  const float minT = rmin * scale;  // == min of scaled row (monotone fl)

  // ---- per-wave 128-bin histogram over candidates (scaled space) ----
  sh[lane] = 0u;
  sh[lane + 64] = 0u;
  const float binscale = (float)NBIN / (Traw * scale);
  for (unsigned e = lane; e < nc; e += 64) {
    int b = (int)(sc[e].x * binscale);
    b = b < 0 ? 0 : (b > NBIN - 1 ? NBIN - 1 : b);
    atomicAdd(&sh[b], 1u);
  }

  // ---- locate rank bin: 2 bins/lane, wave exclusive scan ----
  unsigned c2 = sh[2 * lane] + sh[2 * lane + 1];
  unsigned incl = c2;
#pragma unroll
  for (int d = 1; d < 64; d <<= 1) {
    unsigned o = __shfl_up(incl, d, 64);
    if (lane >= d) incl += o;
  }
  unsigned b2 = incl - c2;
  unsigned tb_l = 0, bt_l = 0;
  bool win = (b2 <= (unsigned)RANK && (unsigned)RANK < b2 + c2);
  if (win) {
    unsigned h0 = sh[2 * lane];
    if ((unsigned)RANK < b2 + h0) { tb_l = 2u * lane; bt_l = b2; }
    else { tb_l = 2u * lane + 1u; bt_l = b2 + h0; }
  }
  unsigned long long wm = __ballot(win);
  int wl = (int)__ffsll(wm) - 1;
  if (wl < 0) wl = 0;  // unreachable guard
  unsigned tb = (unsigned)__shfl((int)tb_l, wl, 64);
  unsigned base_tb = (unsigned)__shfl((int)bt_l, wl, 64);

  // ---- in-bin collect + min-above-bin ----
  *scn = 0u;  // all lanes store 0 (same value)
  float mgt = INFINITY;
  for (unsigned e = lane; e < nc; e += 64) {
    float v = sc[e].x;
    int b = (int)(v * binscale);
    b = b < 0 ? 0 : (b > NBIN - 1 ? NBIN - 1 : b);
    if ((unsigned)b == tb) {
      unsigned p = atomicAdd(scn, 1u);
      if (p < 48u) ssm[p] = v;
    } else if ((unsigned)b > tb) {
      mgt = fminf(mgt, v);
    }
  }
  mgt = wred_min(mgt);
  unsigned cbin = *scn;

  // ---- exact ranks RANK / RANK+1 ----
  float v409, v410;
  if (cbin <= 48u) {
    float cand = (lane < (int)cbin) ? ssm[lane] : INFINITY;
    unsigned less = 0, eq = 0;
    for (unsigned k = 0; k < cbin; k++) {
      float g = ssm[k];
      less += (g < cand) ? 1u : 0u;
      eq += (g == cand) ? 1u : 0u;
    }
    unsigned gl = base_tb + less;
    bool w9 = (lane < (int)cbin) && gl <= (unsigned)RANK && (unsigned)RANK < gl + eq;
    bool w10 = (lane < (int)cbin) && gl <= (unsigned)(RANK + 1) && (unsigned)(RANK + 1) < gl + eq;
    v409 = wred_min(w9 ? cand : INFINITY);
    float t10 = wred_min(w10 ? cand : INFINITY);
    v410 = isinf(t10) ? mgt : t10;
  } else {
    // pathological clustering fallback: O(nc^2/64) exact (never taken here)
    float a9 = INFINITY, a10 = INFINITY;
    for (unsigned e = lane; e < nc; e += 64) {
      float v = sc[e].x;
      int b = (int)(v * binscale);
      b = b < 0 ? 0 : (b > NBIN - 1 ? NBIN - 1 : b);
      if ((unsigned)b == tb) {
        unsigned less = 0, eq = 0;
        for (unsigned k = 0; k < nc; k++) {
          float g = sc[k].x;
          less += (g < v) ? 1u : 0u;
          eq += (g == v) ? 1u : 0u;
        }
        if (less <= (unsigned)RANK && (unsigned)RANK < less + eq) a9 = v;
        if (less <= (unsigned)(RANK + 1) && (unsigned)(RANK + 1) < less + eq) a10 = v;
      }
    }
    v409 = wred_min(a9);
    float t10 = wred_min(a10);
    v410 = isinf(t10) ? mgt : t10;
  }
  const float thr = 0.5f * v409 + 0.5f * v410;  // jax lerp midpoint, frac=0.5

  // ---- weight pass (fixed strided order -> deterministic psum) ----
  float psum = 0.f;
  for (unsigned e = lane; e < nc; e += 64) {
    float2 t = sc[e];
    float w = (t.x <= thr) ? __expf(minT - t.x) : 0.f;
    psum += w;
    sc[e] = make_float2(w, t.y);
  }
  const float denom = wred_sum(psum);
  const float invd = 1.0f / denom;
  const unsigned padded = (nc + 15u) & ~15u;
  if ((unsigned)lane < padded - nc) sc[nc + lane] = make_float2(0.f, __int_as_float(0));

  // ---- gather: 16 lanes x float4 per row, 4 rows per iter, wave-local ----
  const char* vpb = (const char*)(value + (size_t)h * (NSEQ * NB * VD)) + (lane & 15) * 16;
  floatx4 acc4 = {0.f, 0.f, 0.f, 0.f};
  for (unsigned t0 = 0; t0 < padded; t0 += 16) {
    unsigned j = t0 + (unsigned)(lane >> 4);
    float2 c0 = sc[j];        // 16-lane groups read same addr -> broadcast
    float2 c1 = sc[j + 4];
    float2 c2e = sc[j + 8];
    float2 c3 = sc[j + 12];
    floatx4 a0 = *reinterpret_cast<const floatx4*>(vpb + __float_as_int(c0.y));
    floatx4 a1 = *reinterpret_cast<const floatx4*>(vpb + __float_as_int(c1.y));
    floatx4 a2 = *reinterpret_cast<const floatx4*>(vpb + __float_as_int(c2e.y));
    floatx4 a3 = *reinterpret_cast<const floatx4*>(vpb + __float_as_int(c3.y));
    acc4.x = fmaf(c0.x, a0.x, acc4.x);
    acc4.y = fmaf(c0.x, a0.y, acc4.y);
    acc4.z = fmaf(c0.x, a0.z, acc4.z);
    acc4.w = fmaf(c0.x, a0.w, acc4.w);
    acc4.x = fmaf(c1.x, a1.x, acc4.x);
    acc4.y = fmaf(c1.x, a1.y, acc4.y);
    acc4.z = fmaf(c1.x, a1.z, acc4.z);
    acc4.w = fmaf(c1.x, a1.w, acc4.w);
    acc4.x = fmaf(c2e.x, a2.x, acc4.x);
    acc4.y = fmaf(c2e.x, a2.y, acc4.y);
    acc4.z = fmaf(c2e.x, a2.z, acc4.z);
    acc4.w = fmaf(c2e.x, a2.w, acc4.w);
    acc4.x = fmaf(c3.x, a3.x, acc4.x);
    acc4.y = fmaf(c3.x, a3.y, acc4.y);
    acc4.z = fmaf(c3.x, a3.z, acc4.z);
    acc4.w = fmaf(c3.x, a3.w, acc4.w);
  }
  // sum the 4 sixteen-lane groups (xor butterfly on d=16,32)
#pragma unroll
  for (int d = 16; d < 64; d <<= 1) {
    acc4.x += __shfl_xor(acc4.x, d, 64);
    acc4.y += __shfl_xor(acc4.y, d, 64);
    acc4.z += __shfl_xor(acc4.z, d, 64);
    acc4.w += __shfl_xor(acc4.w, d, 64);
  }

  if (lane < 16) {
    float o0 = gelu_tanh(acc4.x * invd);
    float o1 = gelu_tanh(acc4.y * invd);
    float o2 = gelu_tanh(acc4.z * invd);
    float o3 = gelu_tanh(acc4.w * invd);
    int col = lane * 4;
    int bb = col >> 5, kk = col & 31;
    float4 o4 = make_float4(o0, o1, o2, o3);
    *reinterpret_cast<float4*>(&out[((size_t)bb * NSEQ + q) * (NH * VD) + (size_t)h * VD + kk]) = o4;
  }
}

// ---------------- launch ----------------------------------------------------

extern "C" void kernel_launch(void* const* d_in, const int* in_sizes, int n_in,
                              void* d_out, int out_size, void* d_ws, size_t ws_size,
                              hipStream_t stream) {
  const float* m_dist = (const float*)d_in[0];
  const float* x = (const float*)d_in[1];
  const float* r = (const float*)d_in[2];
  const float* w = (const float*)d_in[3];
  float* out = (float*)d_out;

  float* value = (float*)d_ws;                          // NH*NSEQ*NB*VD floats = 8 MB
  float* scales = value + (size_t)NH * NSEQ * NB * VD;  // + 8 floats

  value_kernel<<<dim3(NSEQ / 8), dim3(256), 0, stream>>>(x, w, r, value, scales);
  attn_kernel<<<dim3(NH * NSEQ / 4), dim3(256), 0, stream>>>(m_dist, value, scales, out);
}

// Round 10
// 286.377 us; speedup vs baseline: 2.0552x; 2.0552x over previous
//
#include <hip/hip_runtime.h>
#include <hip/hip_bf16.h>
#include <math.h>

#define NH   8
#define NSEQ 4096
#define NB   2
#define HID  256
#define VD   32
#define RANK 409      // 0-indexed; pos = 0.1*(4096-1) = 409.5 -> lerp(s[409],s[410],0.5)
#define NBIN 128      // candidate-space histogram bins (per wave)
#define CAND 704      // per-wave candidate cap (mean 480, sd 20.6 -> 10.9 sigma)
#define TG   0.1171875f  // raw-space threshold guess (scale-independent, scale>0)

typedef float floatx4 __attribute__((ext_vector_type(4)));

__device__ __forceinline__ unsigned mbcnt64(unsigned long long m) {
  return __builtin_amdgcn_mbcnt_hi((unsigned)(m >> 32),
                                   __builtin_amdgcn_mbcnt_lo((unsigned)m, 0u));
}
__device__ __forceinline__ float wred_min(float x) {
#pragma unroll
  for (int d = 32; d; d >>= 1) x = fminf(x, __shfl_xor(x, d, 64));
  return x;
}
__device__ __forceinline__ float wred_sum(float x) {
#pragma unroll
  for (int d = 32; d; d >>= 1) x += __shfl_xor(x, d, 64);
  return x;
}
__device__ __forceinline__ float gelu_tanh(float x) {
  float x3 = x * x * x;
  float inner = 0.7978845608028654f * (x + 0.044715f * x3);
  return 0.5f * x * (1.0f + tanhf(inner));
}

// ---------------- kernel A: value[h][n][b*32+k] = x @ weight; + scales ------

__global__ __launch_bounds__(256) void value_kernel(
    const float* __restrict__ x, const float* __restrict__ w,
    const float* __restrict__ r, float* __restrict__ value,
    float* __restrict__ scales) {
  const int tid = threadIdx.x;

  if (blockIdx.x == 0 && tid < NH) {
    double rv = (double)r[tid];
    const float c0 = (float)(0.25 * 3.141592653589793 * (1.0 - 1e-07));
    float s1 = (float)sin(rv);
    float t = c0 * (1.0f + s1);
    scales[tid] = (float)tan((double)t);
  }

  const int n0 = blockIdx.x * 8;
  __shared__ float sx[NB][8][HID];
#pragma unroll
  for (int i = 0; i < 16; i++) {
    int idx = i * 256 + tid;
    int b = idx >> 11;
    int rem = idx & 2047;
    int nn = rem >> 8;
    int j = rem & 255;
    sx[b][nn][j] = x[((size_t)b * NSEQ + n0 + nn) * HID + j];
  }
  __syncthreads();

  const int h = tid >> 5, k = tid & 31;
  float acc[NB][8];
#pragma unroll
  for (int b = 0; b < NB; b++)
#pragma unroll
    for (int nn = 0; nn < 8; nn++) acc[b][nn] = 0.f;

  const float* wp = w + (size_t)h * HID * VD + k;
  for (int j4 = 0; j4 < HID; j4 += 4) {
    float wv0 = wp[(size_t)(j4 + 0) * VD];
    float wv1 = wp[(size_t)(j4 + 1) * VD];
    float wv2 = wp[(size_t)(j4 + 2) * VD];
    float wv3 = wp[(size_t)(j4 + 3) * VD];
#pragma unroll
    for (int b = 0; b < NB; b++) {
#pragma unroll
      for (int nn = 0; nn < 8; nn++) {
        const float4 xv = *reinterpret_cast<const float4*>(&sx[b][nn][j4]);
        float a = acc[b][nn];
        a = fmaf(xv.x, wv0, a);
        a = fmaf(xv.y, wv1, a);
        a = fmaf(xv.z, wv2, a);
        a = fmaf(xv.w, wv3, a);
        acc[b][nn] = a;
      }
    }
  }
#pragma unroll
  for (int b = 0; b < NB; b++)
#pragma unroll
    for (int nn = 0; nn < 8; nn++)
      value[((size_t)h * NSEQ + n0 + nn) * (NB * VD) + b * VD + k] = acc[b][nn];
}

// ---------------- kernel B: ONE WAVE PER ROW, zero __syncthreads ------------

__global__ __launch_bounds__(256, 5) void attn_kernel(
    const float* __restrict__ m_dist, const float* __restrict__ value,
    const float* __restrict__ scales, float* __restrict__ out) {
  const int tid = threadIdx.x;
  const int lane = tid & 63;
  const int wv = tid >> 6;
  // 8192 blocks of 4 independent waves; bid&7 -> head == XCD (value L2-resident)
  const int bid = blockIdx.x;
  const int h = bid & 7;
  const int q = (bid >> 3) * 4 + wv;

  __shared__ float2 s_cand[4][CAND];   // 22528 B: per-wave (v_scaled, byteoff)->(w, byteoff)
  __shared__ unsigned s_hist[4][NBIN]; // 2048 B
  __shared__ float s_small[4][48];     // 768 B
  __shared__ unsigned s_cnt[4];        // 16 B   (total 25360 B -> 6 blocks/CU)

  float2* sc = s_cand[wv];
  unsigned* sh = s_hist[wv];
  float* ssm = s_small[wv];
  unsigned* scn = &s_cnt[wv];

  const float scale = scales[h];
  const floatx4* row4 =
      reinterpret_cast<const floatx4*>(m_dist + ((size_t)(h * NSEQ + q)) * NSEQ) + lane;

  // ---- stream 16 chunks: raw-space candidate compaction via ballot prefix ----
  // raw order == scaled order (scale>0, fl monotone), so select on raw u.
  float Traw = TG;
  float lo = 0.f, hi = 1.0f;
  float rmin;
  unsigned nc;
  for (int attempt = 0;; ++attempt) {
    rmin = INFINITY;
    nc = 0;
#pragma unroll 4
    for (int ch = 0; ch < 16; ++ch) {
      floatx4 t4 = __builtin_nontemporal_load(row4 + ch * 64);
      const int nb = ch * 256 + lane * 4;
      float u0 = t4.x, u1 = t4.y, u2 = t4.z, u3 = t4.w;
      rmin = fminf(fminf(fminf(rmin, u0), fminf(u1, u2)), u3);
      {
        bool s = (u0 <= Traw);
        unsigned long long m = __ballot(s);
        if (s) { unsigned p = nc + mbcnt64(m); if (p < CAND) sc[p] = make_float2(u0 * scale, __int_as_float((nb + 0) << 8)); }
        nc += (unsigned)__popcll(m);
      }
      {
        bool s = (u1 <= Traw);
        unsigned long long m = __ballot(s);
        if (s) { unsigned p = nc + mbcnt64(m); if (p < CAND) sc[p] = make_float2(u1 * scale, __int_as_float((nb + 1) << 8)); }
        nc += (unsigned)__popcll(m);
      }
      {
        bool s = (u2 <= Traw);
        unsigned long long m = __ballot(s);
        if (s) { unsigned p = nc + mbcnt64(m); if (p < CAND) sc[p] = make_float2(u2 * scale, __int_as_float((nb + 2) << 8)); }
        nc += (unsigned)__popcll(m);
      }
      {
        bool s = (u3 <= Traw);
        unsigned long long m = __ballot(s);
        if (s) { unsigned p = nc + mbcnt64(m); if (p < CAND) sc[p] = make_float2(u3 * scale, __int_as_float((nb + 3) << 8)); }
        nc += (unsigned)__popcll(m);
      }
    }
    rmin = wred_min(rmin);
    if ((nc >= (unsigned)(RANK + 2) && nc <= CAND) || attempt >= 24) break;
    if (nc < (unsigned)(RANK + 2)) lo = Traw; else hi = Traw;
    float mid = 0.5f * (lo + hi);
    if (!(mid > lo && mid < hi)) break;  // interval collapsed (massive ties; unreachable)
    Traw = mid;
  }
  if (nc > CAND) nc = CAND;  // safety (unreachable on this data)
  const float minT = rmin * scale;  // == min of scaled row (monotone fl)

  // ---- per-wave 128-bin histogram over candidates (scaled space) ----
  sh[lane] = 0u;
  sh[lane + 64] = 0u;
  const float binscale = (float)NBIN / (Traw * scale);
  for (unsigned e = lane; e < nc; e += 64) {
    int b = (int)(sc[e].x * binscale);
    b = b < 0 ? 0 : (b > NBIN - 1 ? NBIN - 1 : b);
    atomicAdd(&sh[b], 1u);
  }

  // ---- locate rank bin: 2 bins/lane, wave exclusive scan ----
  unsigned c2 = sh[2 * lane] + sh[2 * lane + 1];
  unsigned incl = c2;
#pragma unroll
  for (int d = 1; d < 64; d <<= 1) {
    unsigned o = __shfl_up(incl, d, 64);
    if (lane >= d) incl += o;
  }
  unsigned b2 = incl - c2;
  unsigned tb_l = 0, bt_l = 0;
  bool win = (b2 <= (unsigned)RANK && (unsigned)RANK < b2 + c2);
  if (win) {
    unsigned h0 = sh[2 * lane];
    if ((unsigned)RANK < b2 + h0) { tb_l = 2u * lane; bt_l = b2; }
    else { tb_l = 2u * lane + 1u; bt_l = b2 + h0; }
  }
  unsigned long long wm = __ballot(win);
  int wl = (int)__ffsll(wm) - 1;
  if (wl < 0) wl = 0;  // unreachable guard
  unsigned tb = (unsigned)__shfl((int)tb_l, wl, 64);
  unsigned base_tb = (unsigned)__shfl((int)bt_l, wl, 64);

  // ---- in-bin collect + min-above-bin ----
  *scn = 0u;  // all lanes store 0 (same value)
  float mgt = INFINITY;
  for (unsigned e = lane; e < nc; e += 64) {
    float v = sc[e].x;
    int b = (int)(v * binscale);
    b = b < 0 ? 0 : (b > NBIN - 1 ? NBIN - 1 : b);
    if ((unsigned)b == tb) {
      unsigned p = atomicAdd(scn, 1u);
      if (p < 48u) ssm[p] = v;
    } else if ((unsigned)b > tb) {
      mgt = fminf(mgt, v);
    }
  }
  mgt = wred_min(mgt);
  unsigned cbin = *scn;

  // ---- exact ranks RANK / RANK+1 ----
  float v409, v410;
  if (cbin <= 48u) {
    float cand = (lane < (int)cbin) ? ssm[lane] : INFINITY;
    unsigned less = 0, eq = 0;
    for (unsigned k = 0; k < cbin; k++) {
      float g = ssm[k];
      less += (g < cand) ? 1u : 0u;
      eq += (g == cand) ? 1u : 0u;
    }
    unsigned gl = base_tb + less;
    bool w9 = (lane < (int)cbin) && gl <= (unsigned)RANK && (unsigned)RANK < gl + eq;
    bool w10 = (lane < (int)cbin) && gl <= (unsigned)(RANK + 1) && (unsigned)(RANK + 1) < gl + eq;
    v409 = wred_min(w9 ? cand : INFINITY);
    float t10 = wred_min(w10 ? cand : INFINITY);
    v410 = isinf(t10) ? mgt : t10;
  } else {
    // pathological clustering fallback: O(nc^2/64) exact (never taken here)
    float a9 = INFINITY, a10 = INFINITY;
    for (unsigned e = lane; e < nc; e += 64) {
      float v = sc[e].x;
      int b = (int)(v * binscale);
      b = b < 0 ? 0 : (b > NBIN - 1 ? NBIN - 1 : b);
      if ((unsigned)b == tb) {
        unsigned less = 0, eq = 0;
        for (unsigned k = 0; k < nc; k++) {
          float g = sc[k].x;
          less += (g < v) ? 1u : 0u;
          eq += (g == v) ? 1u : 0u;
        }
        if (less <= (unsigned)RANK && (unsigned)RANK < less + eq) a9 = v;
        if (less <= (unsigned)(RANK + 1) && (unsigned)(RANK + 1) < less + eq) a10 = v;
      }
    }
    v409 = wred_min(a9);
    float t10 = wred_min(a10);
    v410 = isinf(t10) ? mgt : t10;
  }
  const float thr = 0.5f * v409 + 0.5f * v410;  // jax lerp midpoint, frac=0.5

  // ---- weight pass (fixed strided order -> deterministic psum) ----
  float psum = 0.f;
  for (unsigned e = lane; e < nc; e += 64) {
    float2 t = sc[e];
    float w = (t.x <= thr) ? __expf(minT - t.x) : 0.f;
    psum += w;
    sc[e] = make_float2(w, t.y);
  }
  const float denom = wred_sum(psum);
  const float invd = 1.0f / denom;
  const unsigned padded = (nc + 15u) & ~15u;
  if ((unsigned)lane < padded - nc) sc[nc + lane] = make_float2(0.f, __int_as_float(0));

  // ---- gather: 16 lanes x float4 per row, 4 rows per iter, wave-local ----
  const char* vpb = (const char*)(value + (size_t)h * (NSEQ * NB * VD)) + (lane & 15) * 16;
  floatx4 acc4 = {0.f, 0.f, 0.f, 0.f};
  for (unsigned t0 = 0; t0 < padded; t0 += 16) {
    unsigned j = t0 + (unsigned)(lane >> 4);
    float2 c0 = sc[j];        // 16-lane groups read same addr -> broadcast
    float2 c1 = sc[j + 4];
    float2 c2e = sc[j + 8];
    float2 c3 = sc[j + 12];
    floatx4 a0 = *reinterpret_cast<const floatx4*>(vpb + __float_as_int(c0.y));
    floatx4 a1 = *reinterpret_cast<const floatx4*>(vpb + __float_as_int(c1.y));
    floatx4 a2 = *reinterpret_cast<const floatx4*>(vpb + __float_as_int(c2e.y));
    floatx4 a3 = *reinterpret_cast<const floatx4*>(vpb + __float_as_int(c3.y));
    acc4.x = fmaf(c0.x, a0.x, acc4.x);
    acc4.y = fmaf(c0.x, a0.y, acc4.y);
    acc4.z = fmaf(c0.x, a0.z, acc4.z);
    acc4.w = fmaf(c0.x, a0.w, acc4.w);
    acc4.x = fmaf(c1.x, a1.x, acc4.x);
    acc4.y = fmaf(c1.x, a1.y, acc4.y);
    acc4.z = fmaf(c1.x, a1.z, acc4.z);
    acc4.w = fmaf(c1.x, a1.w, acc4.w);
    acc4.x = fmaf(c2e.x, a2.x, acc4.x);
    acc4.y = fmaf(c2e.x, a2.y, acc4.y);
    acc4.z = fmaf(c2e.x, a2.z, acc4.z);
    acc4.w = fmaf(c2e.x, a2.w, acc4.w);
    acc4.x = fmaf(c3.x, a3.x, acc4.x);
    acc4.y = fmaf(c3.x, a3.y, acc4.y);
    acc4.z = fmaf(c3.x, a3.z, acc4.z);
    acc4.w = fmaf(c3.x, a3.w, acc4.w);
  }
  // sum the 4 sixteen-lane groups (xor butterfly on d=16,32)
#pragma unroll
  for (int d = 16; d < 64; d <<= 1) {
    acc4.x += __shfl_xor(acc4.x, d, 64);
    acc4.y += __shfl_xor(acc4.y, d, 64);
    acc4.z += __shfl_xor(acc4.z, d, 64);
    acc4.w += __shfl_xor(acc4.w, d, 64);
  }

  if (lane < 16) {
    float o0 = gelu_tanh(acc4.x * invd);
    float o1 = gelu_tanh(acc4.y * invd);
    float o2 = gelu_tanh(acc4.z * invd);
    float o3 = gelu_tanh(acc4.w * invd);
    int col = lane * 4;
    int bb = col >> 5, kk = col & 31;
    float4 o4 = make_float4(o0, o1, o2, o3);
    *reinterpret_cast<float4*>(&out[((size_t)bb * NSEQ + q) * (NH * VD) + (size_t)h * VD + kk]) = o4;
  }
}

// ---------------- launch ----------------------------------------------------

extern "C" void kernel_launch(void* const* d_in, const int* in_sizes, int n_in,
                              void* d_out, int out_size, void* d_ws, size_t ws_size,
                              hipStream_t stream) {
  const float* m_dist = (const float*)d_in[0];
  const float* x = (const float*)d_in[1];
  const float* r = (const float*)d_in[2];
  const float* w = (const float*)d_in[3];
  float* out = (float*)d_out;

  float* value = (float*)d_ws;                          // NH*NSEQ*NB*VD floats = 8 MB
  float* scales = value + (size_t)NH * NSEQ * NB * VD;  // + 8 floats

  value_kernel<<<dim3(NSEQ / 8), dim3(256), 0, stream>>>(x, w, r, value, scales);
  attn_kernel<<<dim3(NH * NSEQ / 4), dim3(256), 0, stream>>>(m_dist, value, scales, out);
}

// Round 11
// 261.627 us; speedup vs baseline: 2.2496x; 1.0946x over previous
//
#include <hip/hip_runtime.h>
#include <hip/hip_bf16.h>
#include <math.h>

#define NH   8
#define NSEQ 4096
#define NB   2
#define HID  256
#define VD   32
#define RANK 409      // 0-indexed; pos = 0.1*(4096-1) = 409.5 -> lerp(s[409],s[410],0.5)
#define NBIN 128      // candidate-space histogram bins (per wave)
#define CAND 704      // per-wave candidate cap (mean 480, sd 20.6 -> 10.9 sigma)
#define TG   0.1171875f  // raw-space threshold guess (scale-independent, scale>0)

typedef float floatx4 __attribute__((ext_vector_type(4)));

__device__ __forceinline__ unsigned mbcnt64(unsigned long long m) {
  return __builtin_amdgcn_mbcnt_hi((unsigned)(m >> 32),
                                   __builtin_amdgcn_mbcnt_lo((unsigned)m, 0u));
}
__device__ __forceinline__ float wred_min(float x) {
#pragma unroll
  for (int d = 32; d; d >>= 1) x = fminf(x, __shfl_xor(x, d, 64));
  return x;
}
__device__ __forceinline__ float wred_sum(float x) {
#pragma unroll
  for (int d = 32; d; d >>= 1) x += __shfl_xor(x, d, 64);
  return x;
}
__device__ __forceinline__ float gelu_tanh(float x) {
  float x3 = x * x * x;
  float inner = 0.7978845608028654f * (x + 0.044715f * x3);
  return 0.5f * x * (1.0f + tanhf(inner));
}

// ---------------- kernel A: value[h][n][b*32+k] = x @ weight; + scales ------

__global__ __launch_bounds__(256) void value_kernel(
    const float* __restrict__ x, const float* __restrict__ w,
    const float* __restrict__ r, float* __restrict__ value,
    float* __restrict__ scales) {
  const int tid = threadIdx.x;

  if (blockIdx.x == 0 && tid < NH) {
    double rv = (double)r[tid];
    const float c0 = (float)(0.25 * 3.141592653589793 * (1.0 - 1e-07));
    float s1 = (float)sin(rv);
    float t = c0 * (1.0f + s1);
    scales[tid] = (float)tan((double)t);
  }

  const int n0 = blockIdx.x * 8;
  __shared__ float sx[NB][8][HID];
#pragma unroll
  for (int i = 0; i < 16; i++) {
    int idx = i * 256 + tid;
    int b = idx >> 11;
    int rem = idx & 2047;
    int nn = rem >> 8;
    int j = rem & 255;
    sx[b][nn][j] = x[((size_t)b * NSEQ + n0 + nn) * HID + j];
  }
  __syncthreads();

  const int h = tid >> 5, k = tid & 31;
  float acc[NB][8];
#pragma unroll
  for (int b = 0; b < NB; b++)
#pragma unroll
    for (int nn = 0; nn < 8; nn++) acc[b][nn] = 0.f;

  const float* wp = w + (size_t)h * HID * VD + k;
  for (int j4 = 0; j4 < HID; j4 += 4) {
    float wv0 = wp[(size_t)(j4 + 0) * VD];
    float wv1 = wp[(size_t)(j4 + 1) * VD];
    float wv2 = wp[(size_t)(j4 + 2) * VD];
    float wv3 = wp[(size_t)(j4 + 3) * VD];
#pragma unroll
    for (int b = 0; b < NB; b++) {
#pragma unroll
      for (int nn = 0; nn < 8; nn++) {
        const float4 xv = *reinterpret_cast<const float4*>(&sx[b][nn][j4]);
        float a = acc[b][nn];
        a = fmaf(xv.x, wv0, a);
        a = fmaf(xv.y, wv1, a);
        a = fmaf(xv.z, wv2, a);
        a = fmaf(xv.w, wv3, a);
        acc[b][nn] = a;
      }
    }
  }
#pragma unroll
  for (int b = 0; b < NB; b++)
#pragma unroll
    for (int nn = 0; nn < 8; nn++)
      value[((size_t)h * NSEQ + n0 + nn) * (NB * VD) + b * VD + k] = acc[b][nn];
}

// ---------------- kernel B: ONE WAVE PER ROW, zero __syncthreads ------------
// Hot path: straight-line pipelined stream @ compile-time threshold TG.
// Cold path (bisect + restream, L3-warm) only if nc outside [411, CAND].

// process one float4 chunk CH (elements CH*256 + lane*4 + 0..3)
#define PROC(CV, CH, THR)                                                          \
  do {                                                                             \
    const int nb_ = ((CH) << 16) | (lane << 10);                                   \
    {                                                                              \
      bool s = (CV).x <= (THR);                                                    \
      unsigned long long m = __ballot(s);                                          \
      unsigned p = nc + mbcnt64(m);                                                \
      if (s && p < CAND) sc[p] = make_float2((CV).x * scale, __int_as_float(nb_)); \
      nc += (unsigned)__popcll(m);                                                 \
    }                                                                              \
    {                                                                              \
      bool s = (CV).y <= (THR);                                                    \
      unsigned long long m = __ballot(s);                                          \
      unsigned p = nc + mbcnt64(m);                                                \
      if (s && p < CAND) sc[p] = make_float2((CV).y * scale, __int_as_float(nb_ | 256)); \
      nc += (unsigned)__popcll(m);                                                 \
    }                                                                              \
    {                                                                              \
      bool s = (CV).z <= (THR);                                                    \
      unsigned long long m = __ballot(s);                                          \
      unsigned p = nc + mbcnt64(m);                                                \
      if (s && p < CAND) sc[p] = make_float2((CV).z * scale, __int_as_float(nb_ | 512)); \
      nc += (unsigned)__popcll(m);                                                 \
    }                                                                              \
    {                                                                              \
      bool s = (CV).w <= (THR);                                                    \
      unsigned long long m = __ballot(s);                                          \
      unsigned p = nc + mbcnt64(m);                                                \
      if (s && p < CAND) sc[p] = make_float2((CV).w * scale, __int_as_float(nb_ | 768)); \
      nc += (unsigned)__popcll(m);                                                 \
    }                                                                              \
  } while (0)

__global__ __launch_bounds__(256, 5) void attn_kernel(
    const float* __restrict__ m_dist, const float* __restrict__ value,
    const float* __restrict__ scales, float* __restrict__ out) {
  const int tid = threadIdx.x;
  const int lane = tid & 63;
  const int wv = tid >> 6;
  // 8192 blocks of 4 independent waves; bid&7 -> head == XCD (value L2-resident)
  const int bid = blockIdx.x;
  const int h = bid & 7;
  const int q = (bid >> 3) * 4 + wv;

  __shared__ float2 s_cand[4][CAND];   // 22528 B: per-wave (v_scaled, byteoff)->(w, byteoff)
  __shared__ unsigned s_hist[4][NBIN]; // 2048 B
  __shared__ float s_small[4][48];     // 768 B
  __shared__ unsigned s_cnt[4];        // 16 B   (total 25360 B -> 6 blocks/CU)

  float2* sc = s_cand[wv];
  unsigned* sh = s_hist[wv];
  float* ssm = s_small[wv];
  unsigned* scn = &s_cnt[wv];

  const float scale = scales[h];
  const floatx4* row4 =
      reinterpret_cast<const floatx4*>(m_dist + ((size_t)(h * NSEQ + q)) * NSEQ) + lane;

  // ---- HOT stream: explicit double-buffered pipeline, threshold = TG ----
  unsigned nc = 0;
  {
    floatx4 c0 = __builtin_nontemporal_load(row4 + 0 * 64);
    floatx4 c1 = __builtin_nontemporal_load(row4 + 1 * 64);
    floatx4 c2 = __builtin_nontemporal_load(row4 + 2 * 64);
    floatx4 c3 = __builtin_nontemporal_load(row4 + 3 * 64);
    floatx4 n0 = __builtin_nontemporal_load(row4 + 4 * 64);
    floatx4 n1 = __builtin_nontemporal_load(row4 + 5 * 64);
    floatx4 n2 = __builtin_nontemporal_load(row4 + 6 * 64);
    floatx4 n3 = __builtin_nontemporal_load(row4 + 7 * 64);
    PROC(c0, 0, TG); PROC(c1, 1, TG); PROC(c2, 2, TG); PROC(c3, 3, TG);
    c0 = n0; c1 = n1; c2 = n2; c3 = n3;
    n0 = __builtin_nontemporal_load(row4 + 8 * 64);
    n1 = __builtin_nontemporal_load(row4 + 9 * 64);
    n2 = __builtin_nontemporal_load(row4 + 10 * 64);
    n3 = __builtin_nontemporal_load(row4 + 11 * 64);
    PROC(c0, 4, TG); PROC(c1, 5, TG); PROC(c2, 6, TG); PROC(c3, 7, TG);
    c0 = n0; c1 = n1; c2 = n2; c3 = n3;
    n0 = __builtin_nontemporal_load(row4 + 12 * 64);
    n1 = __builtin_nontemporal_load(row4 + 13 * 64);
    n2 = __builtin_nontemporal_load(row4 + 14 * 64);
    n3 = __builtin_nontemporal_load(row4 + 15 * 64);
    PROC(c0, 8, TG); PROC(c1, 9, TG); PROC(c2, 10, TG); PROC(c3, 11, TG);
    c0 = n0; c1 = n1; c2 = n2; c3 = n3;
    PROC(c0, 12, TG); PROC(c1, 13, TG); PROC(c2, 14, TG); PROC(c3, 15, TG);
  }

  float Tsel = TG;
  if (nc < (unsigned)(RANK + 2) || nc > CAND) {
    // ---- COLD: bisect threshold, restream (L3-warm). Never taken on uniform data.
    float lo = 0.f, hi = 1.0f;
    float Traw = TG;
    for (int attempt = 0; attempt < 24; ++attempt) {
      if (nc < (unsigned)(RANK + 2)) lo = Traw; else hi = Traw;
      float mid = 0.5f * (lo + hi);
      if (!(mid > lo && mid < hi)) break;  // interval collapsed (massive ties)
      Traw = mid;
      nc = 0;
#pragma unroll 2
      for (int ch = 0; ch < 16; ++ch) {
        floatx4 cv = __builtin_nontemporal_load(row4 + ch * 64);
        PROC(cv, ch, Traw);
      }
      if (nc >= (unsigned)(RANK + 2) && nc <= CAND) break;
    }
    Tsel = Traw;
  }
  if (nc > CAND) nc = CAND;  // safety (unreachable on this data)

  // ---- per-wave 128-bin histogram over candidates + fused global-min ----
  // global row min == min of candidates (min <= Tsel whenever nc>0)
  sh[lane] = 0u;
  sh[lane + 64] = 0u;
  const float binscale = (float)NBIN / (Tsel * scale);
  float mn = INFINITY;
  for (unsigned e = lane; e < nc; e += 64) {
    float vv = sc[e].x;
    mn = fminf(mn, vv);
    int b = (int)(vv * binscale);
    b = b < 0 ? 0 : (b > NBIN - 1 ? NBIN - 1 : b);
    atomicAdd(&sh[b], 1u);
  }
  const float minT = wred_min(mn);

  // ---- locate rank bin: 2 bins/lane, wave exclusive scan ----
  unsigned c2 = sh[2 * lane] + sh[2 * lane + 1];
  unsigned incl = c2;
#pragma unroll
  for (int d = 1; d < 64; d <<= 1) {
    unsigned o = __shfl_up(incl, d, 64);
    if (lane >= d) incl += o;
  }
  unsigned b2 = incl - c2;
  unsigned tb_l = 0, bt_l = 0;
  bool win = (b2 <= (unsigned)RANK && (unsigned)RANK < b2 + c2);
  if (win) {
    unsigned h0 = sh[2 * lane];
    if ((unsigned)RANK < b2 + h0) { tb_l = 2u * lane; bt_l = b2; }
    else { tb_l = 2u * lane + 1u; bt_l = b2 + h0; }
  }
  unsigned long long wm = __ballot(win);
  int wl = (int)__ffsll(wm) - 1;
  if (wl < 0) wl = 0;  // unreachable guard
  unsigned tb = (unsigned)__shfl((int)tb_l, wl, 64);
  unsigned base_tb = (unsigned)__shfl((int)bt_l, wl, 64);

  // ---- in-bin collect + min-above-bin ----
  *scn = 0u;  // all lanes store 0 (same value)
  float mgt = INFINITY;
  for (unsigned e = lane; e < nc; e += 64) {
    float v = sc[e].x;
    int b = (int)(v * binscale);
    b = b < 0 ? 0 : (b > NBIN - 1 ? NBIN - 1 : b);
    if ((unsigned)b == tb) {
      unsigned p = atomicAdd(scn, 1u);
      if (p < 48u) ssm[p] = v;
    } else if ((unsigned)b > tb) {
      mgt = fminf(mgt, v);
    }
  }
  mgt = wred_min(mgt);
  unsigned cbin = *scn;

  // ---- exact ranks RANK / RANK+1 ----
  float v409, v410;
  if (cbin <= 48u) {
    float cand = (lane < (int)cbin) ? ssm[lane] : INFINITY;
    unsigned less = 0, eq = 0;
    for (unsigned k = 0; k < cbin; k++) {
      float g = ssm[k];
      less += (g < cand) ? 1u : 0u;
      eq += (g == cand) ? 1u : 0u;
    }
    unsigned gl = base_tb + less;
    bool w9 = (lane < (int)cbin) && gl <= (unsigned)RANK && (unsigned)RANK < gl + eq;
    bool w10 = (lane < (int)cbin) && gl <= (unsigned)(RANK + 1) && (unsigned)(RANK + 1) < gl + eq;
    v409 = wred_min(w9 ? cand : INFINITY);
    float t10 = wred_min(w10 ? cand : INFINITY);
    v410 = isinf(t10) ? mgt : t10;
  } else {
    // pathological clustering fallback: O(nc^2/64) exact (never taken here)
    float a9 = INFINITY, a10 = INFINITY;
    for (unsigned e = lane; e < nc; e += 64) {
      float v = sc[e].x;
      int b = (int)(v * binscale);
      b = b < 0 ? 0 : (b > NBIN - 1 ? NBIN - 1 : b);
      if ((unsigned)b == tb) {
        unsigned less = 0, eq = 0;
        for (unsigned k = 0; k < nc; k++) {
          float g = sc[k].x;
          less += (g < v) ? 1u : 0u;
          eq += (g == v) ? 1u : 0u;
        }
        if (less <= (unsigned)RANK && (unsigned)RANK < less + eq) a9 = v;
        if (less <= (unsigned)(RANK + 1) && (unsigned)(RANK + 1) < less + eq) a10 = v;
      }
    }
    v409 = wred_min(a9);
    float t10 = wred_min(a10);
    v410 = isinf(t10) ? mgt : t10;
  }
  const float thr = 0.5f * v409 + 0.5f * v410;  // jax lerp midpoint, frac=0.5

  // ---- weight pass (fixed strided order -> deterministic psum) ----
  float psum = 0.f;
  for (unsigned e = lane; e < nc; e += 64) {
    float2 t = sc[e];
    float w = (t.x <= thr) ? __expf(minT - t.x) : 0.f;
    psum += w;
    sc[e] = make_float2(w, t.y);
  }
  const float denom = wred_sum(psum);
  const float invd = 1.0f / denom;
  const unsigned padded = (nc + 15u) & ~15u;
  if ((unsigned)lane < padded - nc) sc[nc + lane] = make_float2(0.f, __int_as_float(0));

  // ---- gather: 16 lanes x float4 per row, 4 rows per iter, wave-local ----
  const char* vpb = (const char*)(value + (size_t)h * (NSEQ * NB * VD)) + (lane & 15) * 16;
  floatx4 acc4 = {0.f, 0.f, 0.f, 0.f};
  for (unsigned t0 = 0; t0 < padded; t0 += 16) {
    unsigned j = t0 + (unsigned)(lane >> 4);
    float2 c0 = sc[j];        // 16-lane groups read same addr -> broadcast
    float2 c1 = sc[j + 4];
    float2 c2e = sc[j + 8];
    float2 c3 = sc[j + 12];
    floatx4 a0 = *reinterpret_cast<const floatx4*>(vpb + __float_as_int(c0.y));
    floatx4 a1 = *reinterpret_cast<const floatx4*>(vpb + __float_as_int(c1.y));
    floatx4 a2 = *reinterpret_cast<const floatx4*>(vpb + __float_as_int(c2e.y));
    floatx4 a3 = *reinterpret_cast<const floatx4*>(vpb + __float_as_int(c3.y));
    acc4.x = fmaf(c0.x, a0.x, acc4.x);
    acc4.y = fmaf(c0.x, a0.y, acc4.y);
    acc4.z = fmaf(c0.x, a0.z, acc4.z);
    acc4.w = fmaf(c0.x, a0.w, acc4.w);
    acc4.x = fmaf(c1.x, a1.x, acc4.x);
    acc4.y = fmaf(c1.x, a1.y, acc4.y);
    acc4.z = fmaf(c1.x, a1.z, acc4.z);
    acc4.w = fmaf(c1.x, a1.w, acc4.w);
    acc4.x = fmaf(c2e.x, a2.x, acc4.x);
    acc4.y = fmaf(c2e.x, a2.y, acc4.y);
    acc4.z = fmaf(c2e.x, a2.z, acc4.z);
    acc4.w = fmaf(c2e.x, a2.w, acc4.w);
    acc4.x = fmaf(c3.x, a3.x, acc4.x);
    acc4.y = fmaf(c3.x, a3.y, acc4.y);
    acc4.z = fmaf(c3.x, a3.z, acc4.z);
    acc4.w = fmaf(c3.x, a3.w, acc4.w);
  }
  // sum the 4 sixteen-lane groups (xor butterfly on d=16,32)
#pragma unroll
  for (int d = 16; d < 64; d <<= 1) {
    acc4.x += __shfl_xor(acc4.x, d, 64);
    acc4.y += __shfl_xor(acc4.y, d, 64);
    acc4.z += __shfl_xor(acc4.z, d, 64);
    acc4.w += __shfl_xor(acc4.w, d, 64);
  }

  if (lane < 16) {
    float o0 = gelu_tanh(acc4.x * invd);
    float o1 = gelu_tanh(acc4.y * invd);
    float o2 = gelu_tanh(acc4.z * invd);
    float o3 = gelu_tanh(acc4.w * invd);
    int col = lane * 4;
    int bb = col >> 5, kk = col & 31;
    float4 o4 = make_float4(o0, o1, o2, o3);
    *reinterpret_cast<float4*>(&out[((size_t)bb * NSEQ + q) * (NH * VD) + (size_t)h * VD + kk]) = o4;
  }
}

// ---------------- launch ----------------------------------------------------

extern "C" void kernel_launch(void* const* d_in, const int* in_sizes, int n_in,
                              void* d_out, int out_size, void* d_ws, size_t ws_size,
                              hipStream_t stream) {
  const float* m_dist = (const float*)d_in[0];
  const float* x = (const float*)d_in[1];
  const float* r = (const float*)d_in[2];
  const float* w = (const float*)d_in[3];
  float* out = (float*)d_out;

  float* value = (float*)d_ws;                          // NH*NSEQ*NB*VD floats = 8 MB
  float* scales = value + (size_t)NH * NSEQ * NB * VD;  // + 8 floats

  value_kernel<<<dim3(NSEQ / 8), dim3(256), 0, stream>>>(x, w, r, value, scales);
  attn_kernel<<<dim3(NH * NSEQ / 4), dim3(256), 0, stream>>>(m_dist, value, scales, out);
}

// Round 12
// 260.799 us; speedup vs baseline: 2.2567x; 1.0032x over previous
//
#include <hip/hip_runtime.h>
#include <hip/hip_bf16.h>
#include <math.h>

#define NH   8
#define NSEQ 4096
#define NB   2
#define HID  256
#define VD   32
#define RANK 409       // 0-indexed; pos = 0.1*(4096-1) = 409.5 -> lerp(s[409],s[410],0.5)
#define NBIN 128       // shared per-row histogram bins
#define SEGC 512       // per-half-row candidate cap (mean 240, sd 14.6)
#define TG   0.1171875f  // raw-space threshold guess (scale>0 -> raw order == scaled order)

typedef float floatx4 __attribute__((ext_vector_type(4)));

__device__ __forceinline__ unsigned mbcnt64(unsigned long long m) {
  return __builtin_amdgcn_mbcnt_hi((unsigned)(m >> 32),
                                   __builtin_amdgcn_mbcnt_lo((unsigned)m, 0u));
}
__device__ __forceinline__ float wred_min(float x) {
#pragma unroll
  for (int d = 32; d; d >>= 1) x = fminf(x, __shfl_xor(x, d, 64));
  return x;
}
__device__ __forceinline__ float wred_max(float x) {
#pragma unroll
  for (int d = 32; d; d >>= 1) x = fmaxf(x, __shfl_xor(x, d, 64));
  return x;
}
__device__ __forceinline__ float wred_sum(float x) {
#pragma unroll
  for (int d = 32; d; d >>= 1) x += __shfl_xor(x, d, 64);
  return x;
}
__device__ __forceinline__ float gelu_tanh(float x) {
  float x3 = x * x * x;
  float inner = 0.7978845608028654f * (x + 0.044715f * x3);
  return 0.5f * x * (1.0f + tanhf(inner));
}

// ---------------- kernel A: value[h][n][b*32+k] = x @ weight; + scales ------

__global__ __launch_bounds__(256) void value_kernel(
    const float* __restrict__ x, const float* __restrict__ w,
    const float* __restrict__ r, float* __restrict__ value,
    float* __restrict__ scales) {
  const int tid = threadIdx.x;

  if (blockIdx.x == 0 && tid < NH) {
    double rv = (double)r[tid];
    const float c0 = (float)(0.25 * 3.141592653589793 * (1.0 - 1e-07));
    float s1 = (float)sin(rv);
    float t = c0 * (1.0f + s1);
    scales[tid] = (float)tan((double)t);
  }

  const int n0 = blockIdx.x * 8;
  __shared__ float sx[NB][8][HID];
#pragma unroll
  for (int i = 0; i < 16; i++) {
    int idx = i * 256 + tid;
    int b = idx >> 11;
    int rem = idx & 2047;
    int nn = rem >> 8;
    int j = rem & 255;
    sx[b][nn][j] = x[((size_t)b * NSEQ + n0 + nn) * HID + j];
  }
  __syncthreads();

  const int h = tid >> 5, k = tid & 31;
  float acc[NB][8];
#pragma unroll
  for (int b = 0; b < NB; b++)
#pragma unroll
    for (int nn = 0; nn < 8; nn++) acc[b][nn] = 0.f;

  const float* wp = w + (size_t)h * HID * VD + k;
  for (int j4 = 0; j4 < HID; j4 += 4) {
    float wv0 = wp[(size_t)(j4 + 0) * VD];
    float wv1 = wp[(size_t)(j4 + 1) * VD];
    float wv2 = wp[(size_t)(j4 + 2) * VD];
    float wv3 = wp[(size_t)(j4 + 3) * VD];
#pragma unroll
    for (int b = 0; b < NB; b++) {
#pragma unroll
      for (int nn = 0; nn < 8; nn++) {
        const float4 xv = *reinterpret_cast<const float4*>(&sx[b][nn][j4]);
        float a = acc[b][nn];
        a = fmaf(xv.x, wv0, a);
        a = fmaf(xv.y, wv1, a);
        a = fmaf(xv.z, wv2, a);
        a = fmaf(xv.w, wv3, a);
        acc[b][nn] = a;
      }
    }
  }
#pragma unroll
  for (int b = 0; b < NB; b++)
#pragma unroll
    for (int nn = 0; nn < 8; nn++)
      value[((size_t)h * NSEQ + n0 + nn) * (NB * VD) + b * VD + k] = acc[b][nn];
}

// ---------------- kernel B: 2 waves per row, 1 row per 128-thread block -----

// raw-space test u <= (T); store (u*scale, byteoff)
#define PROCR(CV, G, T)                                                                   \
  do {                                                                                    \
    const int nb_ = ((G) << 16) | (lane << 10);                                           \
    { bool s = (CV).x <= (T); unsigned long long m = __ballot(s);                         \
      unsigned p = nc + mbcnt64(m);                                                       \
      if (s && p < SEGC) seg[p] = make_float2((CV).x * scale, __int_as_float(nb_));       \
      nc += (unsigned)__popcll(m); }                                                      \
    { bool s = (CV).y <= (T); unsigned long long m = __ballot(s);                         \
      unsigned p = nc + mbcnt64(m);                                                       \
      if (s && p < SEGC) seg[p] = make_float2((CV).y * scale, __int_as_float(nb_ | 256)); \
      nc += (unsigned)__popcll(m); }                                                      \
    { bool s = (CV).z <= (T); unsigned long long m = __ballot(s);                         \
      unsigned p = nc + mbcnt64(m);                                                       \
      if (s && p < SEGC) seg[p] = make_float2((CV).z * scale, __int_as_float(nb_ | 512)); \
      nc += (unsigned)__popcll(m); }                                                      \
    { bool s = (CV).w <= (T); unsigned long long m = __ballot(s);                         \
      unsigned p = nc + mbcnt64(m);                                                       \
      if (s && p < SEGC) seg[p] = make_float2((CV).w * scale, __int_as_float(nb_ | 768)); \
      nc += (unsigned)__popcll(m); }                                                      \
  } while (0)

// scaled-space test u*scale <= (TS); store (u*scale, byteoff)  [collapse path]
#define PROCS(CV, G, TS)                                                                  \
  do {                                                                                    \
    const int nb_ = ((G) << 16) | (lane << 10);                                           \
    { float t_ = (CV).x * scale; bool s = t_ <= (TS); unsigned long long m = __ballot(s); \
      unsigned p = nc + mbcnt64(m);                                                       \
      if (s && p < SEGC) seg[p] = make_float2(t_, __int_as_float(nb_));                   \
      nc += (unsigned)__popcll(m); }                                                      \
    { float t_ = (CV).y * scale; bool s = t_ <= (TS); unsigned long long m = __ballot(s); \
      unsigned p = nc + mbcnt64(m);                                                       \
      if (s && p < SEGC) seg[p] = make_float2(t_, __int_as_float(nb_ | 256));             \
      nc += (unsigned)__popcll(m); }                                                      \
    { float t_ = (CV).z * scale; bool s = t_ <= (TS); unsigned long long m = __ballot(s); \
      unsigned p = nc + mbcnt64(m);                                                       \
      if (s && p < SEGC) seg[p] = make_float2(t_, __int_as_float(nb_ | 512));             \
      nc += (unsigned)__popcll(m); }                                                      \
    { float t_ = (CV).w * scale; bool s = t_ <= (TS); unsigned long long m = __ballot(s); \
      unsigned p = nc + mbcnt64(m);                                                       \
      if (s && p < SEGC) seg[p] = make_float2(t_, __int_as_float(nb_ | 768));             \
      nc += (unsigned)__popcll(m); }                                                      \
  } while (0)

// count u <= Tc (wave-total via ballot), track max<=Tc and min>Tc
#define CNT1(U)                                                        \
  do {                                                                 \
    bool s_ = (U) <= Tc;                                               \
    cN += (unsigned)__popcll(__ballot(s_));                            \
    if (s_) vb = fmaxf(vb, (U)); else vs = fminf(vs, (U));             \
  } while (0)

__global__ __launch_bounds__(128, 5) void attn_kernel(
    const float* __restrict__ m_dist, const float* __restrict__ value,
    const float* __restrict__ scales, float* __restrict__ out) {
  const int tid = threadIdx.x;
  const int lane = tid & 63;
  const int sw = tid >> 6;  // which half-row this wave owns
  const int bid = blockIdx.x;
  const int h = bid & 7;    // head == presumed XCD (value slice L2-resident)
  const int q = bid >> 3;

  __shared__ float4 s_cand4[2][(SEGC + 16) / 2];  // 8448 B, 16B-aligned segments
  __shared__ unsigned s_hist[NBIN];               // 512 B (shared per row)
  __shared__ float s_small[48];
  __shared__ float4 s_accw1[16];
  __shared__ unsigned s_nc[2];
  __shared__ float s_minp[2], s_mgtp[2], s_psum[2];
  __shared__ unsigned s_cbin;
  __shared__ unsigned s_cc[2];
  __shared__ float s_cvb[2], s_cvs[2];

  float2* seg = reinterpret_cast<float2*>(s_cand4[sw]);

  const float scale = scales[h];
  const floatx4* row4h =
      reinterpret_cast<const floatx4*>(m_dist + ((size_t)(h * NSEQ + q)) * NSEQ) +
      (size_t)sw * 8 * 64 + lane;
  const int g0 = sw * 8;

  // init (pre-B1)
  s_hist[tid] = 0u;  // NBIN == 128 == blockDim
  if (tid == 0) s_cbin = 0u;

  // ---- hot stream: half row, 2-chunk batches, 4 loads in flight ----
  unsigned nc = 0;
  {
    floatx4 c0 = __builtin_nontemporal_load(row4h + 0 * 64);
    floatx4 c1 = __builtin_nontemporal_load(row4h + 1 * 64);
    floatx4 n0 = __builtin_nontemporal_load(row4h + 2 * 64);
    floatx4 n1 = __builtin_nontemporal_load(row4h + 3 * 64);
    PROCR(c0, g0 + 0, TG); PROCR(c1, g0 + 1, TG);
    c0 = n0; c1 = n1;
    n0 = __builtin_nontemporal_load(row4h + 4 * 64);
    n1 = __builtin_nontemporal_load(row4h + 5 * 64);
    PROCR(c0, g0 + 2, TG); PROCR(c1, g0 + 3, TG);
    c0 = n0; c1 = n1;
    n0 = __builtin_nontemporal_load(row4h + 6 * 64);
    n1 = __builtin_nontemporal_load(row4h + 7 * 64);
    PROCR(c0, g0 + 4, TG); PROCR(c1, g0 + 5, TG);
    c0 = n0; c1 = n1;
    PROCR(c0, g0 + 6, TG); PROCR(c1, g0 + 7, TG);
  }
  if (lane == 0) s_nc[sw] = nc;
  __syncthreads();  // B1

  unsigned nc0 = s_nc[0], nc1 = s_nc[1];
  unsigned ncT = nc0 + nc1;
  bool hot = (ncT >= (unsigned)(RANK + 2)) && (ncT <= 2u * SEGC) &&
             (nc0 <= (unsigned)SEGC) && (nc1 <= (unsigned)SEGC);

  bool exactcase = false;
  float ex409 = 0.f, ex410 = 0.f;
  float TselS = TG * scale;  // scaled bin range upper bound

  if (!hot) {
    // ---- cold (block-synced; ~1e-4 of rows): bisect to total in [411, SEGC] ----
    float lo, hi;
    if (ncT < (unsigned)(RANK + 2)) { lo = TG; hi = 1.0f; }
    else { lo = 0.f; hi = TG; }
    bool success = false, collapse = false;
    float Tsel = TG;
    for (int it = 0; it < 40; ++it) {
      float mid = 0.5f * (lo + hi);
      if (!(mid > lo && mid < hi)) { collapse = true; break; }
      unsigned cN = 0; float vb = -INFINITY, vs = INFINITY;
      const float Tc = mid;
#pragma unroll 2
      for (int c = 0; c < 8; ++c) {
        floatx4 cv = __builtin_nontemporal_load(row4h + c * 64);
        CNT1(cv.x); CNT1(cv.y); CNT1(cv.z); CNT1(cv.w);
      }
      if (lane == 0) s_cc[sw] = cN;
      __syncthreads();
      unsigned tot = s_cc[0] + s_cc[1];
      __syncthreads();
      if (tot >= (unsigned)(RANK + 2) && tot <= (unsigned)SEGC) {
        Tsel = mid; success = true; break;
      }
      if (tot < (unsigned)(RANK + 2)) lo = mid; else hi = mid;
    }
    if (!success && !collapse) { Tsel = hi; success = true; }  // unreachable guard

    if (collapse) {
      // exact tie handling: probe at lo
      unsigned cN = 0; float vb = -INFINITY, vs = INFINITY;
      {
        const float Tc = lo;
#pragma unroll 2
        for (int c = 0; c < 8; ++c) {
          floatx4 cv = __builtin_nontemporal_load(row4h + c * 64);
          CNT1(cv.x); CNT1(cv.y); CNT1(cv.z); CNT1(cv.w);
        }
      }
      vb = wred_max(vb); vs = wred_min(vs);
      if (lane == 0) { s_cc[sw] = cN; s_cvb[sw] = vb; s_cvs[sw] = vs; }
      __syncthreads();
      unsigned C_lo = s_cc[0] + s_cc[1];
      float vbelow = fmaxf(s_cvb[0], s_cvb[1]);
      float vstar = fminf(s_cvs[0], s_cvs[1]);
      float s409r, s410r;
      if (C_lo >= (unsigned)(RANK + 2)) { s409r = vbelow; s410r = vbelow; }       // adversarial guard
      else if (C_lo == (unsigned)(RANK + 1)) { s409r = vbelow; s410r = vstar; }
      else { s409r = vstar; s410r = vstar; }  // cnt(vstar) >= 411 always at collapse
      ex409 = s409r * scale;
      ex410 = s410r * scale;
      exactcase = true;
      float thrS = 0.5f * ex409 + 0.5f * ex410;
      TselS = fmaxf(thrS, 1e-30f);
      nc = 0;
#pragma unroll 2
      for (int c = 0; c < 8; ++c) {
        floatx4 cv = __builtin_nontemporal_load(row4h + c * 64);
        PROCS(cv, g0 + c, thrS);
      }
    } else {
      TselS = Tsel * scale;
      nc = 0;
      const float Tf = Tsel;
#pragma unroll 2
      for (int c = 0; c < 8; ++c) {
        floatx4 cv = __builtin_nontemporal_load(row4h + c * 64);
        PROCR(cv, g0 + c, Tf);
      }
    }
    if (lane == 0) s_nc[sw] = nc;
  }
  const unsigned myn = nc > (unsigned)SEGC ? (unsigned)SEGC : nc;

  // ---- shared 128-bin histogram over own segment + fused min ----
  const float binscale = (float)NBIN / TselS;
  float mn = INFINITY;
  for (unsigned e = lane; e < myn; e += 64) {
    float vv = seg[e].x;
    mn = fminf(mn, vv);
    int b = (int)(vv * binscale);
    b = b < 0 ? 0 : (b > NBIN - 1 ? NBIN - 1 : b);
    atomicAdd(&s_hist[b], 1u);
  }
  mn = wred_min(mn);
  if (lane == 0) s_minp[sw] = mn;
  __syncthreads();  // B2

  // ---- locate rank bin (redundant per wave; 2 bins/lane, wave scan) ----
  unsigned c2 = s_hist[2 * lane] + s_hist[2 * lane + 1];
  unsigned incl = c2;
#pragma unroll
  for (int d = 1; d < 64; d <<= 1) {
    unsigned o = __shfl_up(incl, d, 64);
    if (lane >= d) incl += o;
  }
  unsigned b2 = incl - c2;
  unsigned tb_l = 0, bt_l = 0;
  bool win = (b2 <= (unsigned)RANK && (unsigned)RANK < b2 + c2);
  if (win) {
    unsigned h0 = s_hist[2 * lane];
    if ((unsigned)RANK < b2 + h0) { tb_l = 2u * lane; bt_l = b2; }
    else { tb_l = 2u * lane + 1u; bt_l = b2 + h0; }
  }
  unsigned long long wm = __ballot(win);
  int wl = (int)__ffsll(wm) - 1;
  if (wl < 0) wl = 0;
  unsigned tb = (unsigned)__shfl((int)tb_l, wl, 64);
  unsigned base_tb = (unsigned)__shfl((int)bt_l, wl, 64);

  // ---- in-bin collect (own seg -> shared s_small) + min-above-bin ----
  float mgt = INFINITY;
  for (unsigned e = lane; e < myn; e += 64) {
    float v = seg[e].x;
    int b = (int)(v * binscale);
    b = b < 0 ? 0 : (b > NBIN - 1 ? NBIN - 1 : b);
    if ((unsigned)b == tb) {
      unsigned p = atomicAdd(&s_cbin, 1u);
      if (p < 48u) s_small[p] = v;
    } else if ((unsigned)b > tb) {
      mgt = fminf(mgt, v);
    }
  }
  mgt = wred_min(mgt);
  if (lane == 0) s_mgtp[sw] = mgt;
  __syncthreads();  // B3

  const float minT = fminf(s_minp[0], s_minp[1]);
  const float mgtT = fminf(s_mgtp[0], s_mgtp[1]);
  const unsigned cbin = s_cbin;

  // ---- exact ranks RANK / RANK+1 (redundant per wave, no barrier) ----
  float v409, v410;
  if (cbin <= 48u) {
    float cand = (lane < (int)cbin) ? s_small[lane] : INFINITY;
    unsigned less = 0, eq = 0;
    for (unsigned k = 0; k < cbin; k++) {
      float g = s_small[k];
      less += (g < cand) ? 1u : 0u;
      eq += (g == cand) ? 1u : 0u;
    }
    unsigned gl = base_tb + less;
    bool w9 = (lane < (int)cbin) && gl <= (unsigned)RANK && (unsigned)RANK < gl + eq;
    bool w10 = (lane < (int)cbin) && gl <= (unsigned)(RANK + 1) && (unsigned)(RANK + 1) < gl + eq;
    v409 = wred_min(w9 ? cand : INFINITY);
    float t10 = wred_min(w10 ? cand : INFINITY);
    v410 = isinf(t10) ? mgtT : t10;
  } else {
    // pathological clustering: each wave scans both segments, O(nc^2/64)
    unsigned n0c = s_nc[0] > (unsigned)SEGC ? (unsigned)SEGC : s_nc[0];
    unsigned n1c = s_nc[1] > (unsigned)SEGC ? (unsigned)SEGC : s_nc[1];
    const float2* sg0 = reinterpret_cast<const float2*>(s_cand4[0]);
    const float2* sg1 = reinterpret_cast<const float2*>(s_cand4[1]);
    float a9 = INFINITY, a10 = INFINITY;
    for (int src = 0; src < 2; ++src) {
      const float2* sg = src ? sg1 : sg0;
      unsigned nn = src ? n1c : n0c;
      for (unsigned e = lane; e < nn; e += 64) {
        float v = sg[e].x;
        int b = (int)(v * binscale);
        b = b < 0 ? 0 : (b > NBIN - 1 ? NBIN - 1 : b);
        if ((unsigned)b == tb) {
          unsigned less = 0, eq = 0;
          for (unsigned k = 0; k < n0c; k++) {
            float g = sg0[k].x;
            less += (g < v) ? 1u : 0u;
            eq += (g == v) ? 1u : 0u;
          }
          for (unsigned k = 0; k < n1c; k++) {
            float g = sg1[k].x;
            less += (g < v) ? 1u : 0u;
            eq += (g == v) ? 1u : 0u;
          }
          if (less <= (unsigned)RANK && (unsigned)RANK < less + eq) a9 = v;
          if (less <= (unsigned)(RANK + 1) && (unsigned)(RANK + 1) < less + eq) a10 = v;
        }
      }
    }
    v409 = wred_min(a9);
    float t10 = wred_min(a10);
    v410 = isinf(t10) ? mgtT : t10;
  }
  if (isinf(v409)) v409 = mgtT;  // unreachable guard
  if (exactcase) { v409 = ex409; v410 = ex410; }
  const float thr = 0.5f * v409 + 0.5f * v410;  // jax lerp midpoint, frac=0.5

  // ---- weight pass over own segment (fixed order -> deterministic psum) ----
  float psum = 0.f;
  for (unsigned e = lane; e < myn; e += 64) {
    float2 t = seg[e];
    float w = (t.x <= thr) ? __expf(minT - t.x) : 0.f;
    psum += w;
    seg[e] = make_float2(w, t.y);
  }
  psum = wred_sum(psum);
  if (lane == 0) s_psum[sw] = psum;
  const unsigned padded = (myn + 15u) & ~15u;
  if ((unsigned)lane < padded - myn) seg[myn + lane] = make_float2(0.f, __int_as_float(0));

  // ---- gather own segment: 16 lanes x float4 per entry row, 2 acc chains ----
  const char* vpb = (const char*)(value + (size_t)h * (NSEQ * NB * VD)) + (lane & 15) * 16;
  const unsigned jg = 2u * (unsigned)(lane >> 4);
  floatx4 accA = {0.f, 0.f, 0.f, 0.f};
  floatx4 accB = {0.f, 0.f, 0.f, 0.f};
  for (unsigned t0 = 0; t0 < padded; t0 += 16) {
    float4 e01 = *reinterpret_cast<const float4*>(&seg[t0 + jg]);
    float4 e23 = *reinterpret_cast<const float4*>(&seg[t0 + jg + 8]);
    floatx4 a0 = *reinterpret_cast<const floatx4*>(vpb + __float_as_int(e01.y));
    floatx4 a1 = *reinterpret_cast<const floatx4*>(vpb + __float_as_int(e01.w));
    floatx4 a2 = *reinterpret_cast<const floatx4*>(vpb + __float_as_int(e23.y));
    floatx4 a3 = *reinterpret_cast<const floatx4*>(vpb + __float_as_int(e23.w));
    accA.x = fmaf(e01.x, a0.x, accA.x);
    accA.y = fmaf(e01.x, a0.y, accA.y);
    accA.z = fmaf(e01.x, a0.z, accA.z);
    accA.w = fmaf(e01.x, a0.w, accA.w);
    accA.x = fmaf(e01.z, a1.x, accA.x);
    accA.y = fmaf(e01.z, a1.y, accA.y);
    accA.z = fmaf(e01.z, a1.z, accA.z);
    accA.w = fmaf(e01.z, a1.w, accA.w);
    accB.x = fmaf(e23.x, a2.x, accB.x);
    accB.y = fmaf(e23.x, a2.y, accB.y);
    accB.z = fmaf(e23.x, a2.z, accB.z);
    accB.w = fmaf(e23.x, a2.w, accB.w);
    accB.x = fmaf(e23.z, a3.x, accB.x);
    accB.y = fmaf(e23.z, a3.y, accB.y);
    accB.z = fmaf(e23.z, a3.z, accB.z);
    accB.w = fmaf(e23.z, a3.w, accB.w);
  }
  floatx4 acc4 = {accA.x + accB.x, accA.y + accB.y, accA.z + accB.z, accA.w + accB.w};
  // sum the 4 sixteen-lane groups
#pragma unroll
  for (int d = 16; d < 64; d <<= 1) {
    acc4.x += __shfl_xor(acc4.x, d, 64);
    acc4.y += __shfl_xor(acc4.y, d, 64);
    acc4.z += __shfl_xor(acc4.z, d, 64);
    acc4.w += __shfl_xor(acc4.w, d, 64);
  }
  if (sw == 1 && lane < 16) s_accw1[lane] = make_float4(acc4.x, acc4.y, acc4.z, acc4.w);
  __syncthreads();  // B4

  if (sw == 0 && lane < 16) {
    float4 o = s_accw1[lane];
    float denom = s_psum[0] + s_psum[1];
    float invd = 1.0f / denom;
    float o0 = gelu_tanh((acc4.x + o.x) * invd);
    float o1 = gelu_tanh((acc4.y + o.y) * invd);
    float o2 = gelu_tanh((acc4.z + o.z) * invd);
    float o3 = gelu_tanh((acc4.w + o.w) * invd);
    int col = lane * 4;
    int bb = col >> 5, kk = col & 31;
    float4 o4 = make_float4(o0, o1, o2, o3);
    *reinterpret_cast<float4*>(&out[((size_t)bb * NSEQ + q) * (NH * VD) + (size_t)h * VD + kk]) = o4;
  }
}

// ---------------- launch ----------------------------------------------------

extern "C" void kernel_launch(void* const* d_in, const int* in_sizes, int n_in,
                              void* d_out, int out_size, void* d_ws, size_t ws_size,
                              hipStream_t stream) {
  const float* m_dist = (const float*)d_in[0];
  const float* x = (const float*)d_in[1];
  const float* r = (const float*)d_in[2];
  const float* w = (const float*)d_in[3];
  float* out = (float*)d_out;

  float* value = (float*)d_ws;                          // NH*NSEQ*NB*VD floats = 8 MB
  float* scales = value + (size_t)NH * NSEQ * NB * VD;  // + 8 floats

  value_kernel<<<dim3(NSEQ / 8), dim3(256), 0, stream>>>(x, w, r, value, scales);
  attn_kernel<<<dim3(NH * NSEQ), dim3(128), 0, stream>>>(m_dist, value, scales, out);
}